// Round 8
// baseline (527.874 us; speedup 1.0000x reference)
//
#include <hip/hip_runtime.h>

#define D 128        // D_IN == D_OUT == 128
#define GCB 64       // nodes per bucket
#define GCB_SHIFT 6
#define NB_MAX 2048  // max buckets (nb = ceil(N/64) must be <= NB_MAX-1)

typedef __attribute__((ext_vector_type(8))) short short8;
typedef __attribute__((ext_vector_type(4))) float f32x4;

__device__ inline ushort f2bf(float f) {   // fp32 -> bf16 RNE
    uint u = __float_as_uint(f);
    uint r = (u + 0x7FFFu + ((u >> 16) & 1u)) >> 16;
    return (ushort)r;
}
__device__ inline float bflo(uint m) { return __uint_as_float((m & 0xFFFFu) << 16); }
__device__ inline float bfhi(uint m) { return __uint_as_float(m & 0xFFFF0000u); }

// ---------------- utility ----------------

__global__ void zero_f4_kernel(float4* __restrict__ out, int n4) {
    int i = blockIdx.x * blockDim.x + threadIdx.x;
    int stride = gridDim.x * blockDim.x;
    float4 z = make_float4(0.f, 0.f, 0.f, 0.f);
    for (; i < n4; i += stride) out[i] = z;
}

// ---------------- GEMM: 512 thr, 128-row tiles, reg-prefetch pipeline ----------------

__global__ __launch_bounds__(512, 4) void gemm_mfma(const float* __restrict__ embeds,
                                                    const ushort* __restrict__ wT,
                                                    ushort* __restrict__ support, int N) {
    __shared__ ushort aLds[128 * D];   // 32 KB, XOR-swizzled rows
    __shared__ ushort bLds[D * D];     // 32 KB, XOR-swizzled rows (W^T: [n][k])
    const int t = threadIdx.x;         // 0..511
    const int w = t >> 6;              // wave 0..7
    const int l = t & 63;
    const int kgrp = l >> 4;           // 0..3
    const int lan15 = l & 15;

    #pragma unroll
    for (int c = 0; c < 4; ++c) {
        int chunk = c * 512 + t;
        int byteoff = chunk * 16;
        int n = byteoff >> 8;
        int dstoff = byteoff ^ ((n & 7) << 4);
        *(float4*)((char*)bLds + dstoff) = *(const float4*)((const char*)wT + byteoff);
    }

    const int ntiles = (N + 127) >> 7;
    const int prow = t >> 4;           // base row 0..31 (+ j*32)
    const int pcolf = (t & 15) * 8;    // col in floats

    float4 pf[8];
    int tile = blockIdx.x;
    if (tile < ntiles) {
        #pragma unroll
        for (int j = 0; j < 4; ++j) {
            int grow = (tile << 7) + prow + j * 32;
            if (grow < N) {
                const float* s = embeds + (size_t)grow * D + pcolf;
                pf[2 * j] = *(const float4*)s;
                pf[2 * j + 1] = *(const float4*)(s + 4);
            } else {
                pf[2 * j] = make_float4(0.f, 0.f, 0.f, 0.f);
                pf[2 * j + 1] = make_float4(0.f, 0.f, 0.f, 0.f);
            }
        }
    }

    while (tile < ntiles) {
        const int row0 = tile << 7;
        const int next = tile + gridDim.x;

        __syncthreads();
        #pragma unroll
        for (int j = 0; j < 4; ++j) {
            const int rl = prow + j * 32;
            const float4 f0 = pf[2 * j], f1 = pf[2 * j + 1];
            short8 v;
            v[0] = (short)f2bf(f0.x); v[1] = (short)f2bf(f0.y);
            v[2] = (short)f2bf(f0.z); v[3] = (short)f2bf(f0.w);
            v[4] = (short)f2bf(f1.x); v[5] = (short)f2bf(f1.y);
            v[6] = (short)f2bf(f1.z); v[7] = (short)f2bf(f1.w);
            int byteoff = rl * 256 + pcolf * 2;
            *(short8*)((char*)aLds + (byteoff ^ ((rl & 7) << 4))) = v;
        }
        __syncthreads();

        if (next < ntiles) {
            #pragma unroll
            for (int j = 0; j < 4; ++j) {
                int grow = (next << 7) + prow + j * 32;
                if (grow < N) {
                    const float* s = embeds + (size_t)grow * D + pcolf;
                    pf[2 * j] = *(const float4*)s;
                    pf[2 * j + 1] = *(const float4*)(s + 4);
                } else {
                    pf[2 * j] = make_float4(0.f, 0.f, 0.f, 0.f);
                    pf[2 * j + 1] = make_float4(0.f, 0.f, 0.f, 0.f);
                }
            }
        }

        f32x4 acc[8];
        #pragma unroll
        for (int ct = 0; ct < 8; ++ct) acc[ct] = (f32x4)0.0f;

        const int arow = w * 16 + lan15;
        #pragma unroll
        for (int ks = 0; ks < 4; ++ks) {
            const int kbyte = ks * 64 + kgrp * 16;
            const int aoff = (arow * 256 + kbyte) ^ ((arow & 7) << 4);
            short8 af = *(const short8*)((const char*)aLds + aoff);
            #pragma unroll
            for (int ct = 0; ct < 8; ++ct) {
                const int n = ct * 16 + lan15;
                const int boff = (n * 256 + kbyte) ^ ((n & 7) << 4);
                short8 bfr = *(const short8*)((const char*)bLds + boff);
                acc[ct] = __builtin_amdgcn_mfma_f32_16x16x32_bf16(af, bfr, acc[ct], 0, 0, 0);
            }
        }

        #pragma unroll
        for (int r = 0; r < 4; ++r) {
            const int grow = row0 + w * 16 + kgrp * 4 + r;
            if (grow < N) {
                #pragma unroll
                for (int ct = 0; ct < 8; ++ct) {
                    support[(size_t)grow * D + ct * 16 + lan15] = f2bf(acc[ct][r]);
                }
            }
        }
        tile = next;
    }
}

// ---------------- coarse histogram (+ fused W^T convert) ----------------

__global__ __launch_bounds__(256) void bucket_hist(const int* __restrict__ dst,
                                                   int* __restrict__ bhist, int E,
                                                   const float* __restrict__ W,
                                                   ushort* __restrict__ wT) {
    __shared__ int h[NB_MAX];
    const int t = threadIdx.x;
    #pragma unroll
    for (int j = t; j < NB_MAX; j += 256) h[j] = 0;

    const int gt = blockIdx.x * 256 + t;
    if (gt < D * D) { int r = gt >> 7, c = gt & 127; wT[c * D + r] = f2bf(W[gt]); }
    __syncthreads();

    const int stride = gridDim.x * 256;
    for (int i = gt; i < E; i += stride) atomicAdd(&h[dst[i] >> GCB_SHIFT], 1);
    __syncthreads();
    #pragma unroll
    for (int j = t; j < NB_MAX; j += 256)
        if (h[j]) atomicAdd(&bhist[j], h[j]);
}

// exclusive scan of nb (<=2047) bucket counts; writes cbase[0..nb], ccursor copy
__global__ __launch_bounds__(512) void cscan(const int* __restrict__ bhist,
                                             int* __restrict__ cbase,
                                             int* __restrict__ ccursor, int nb) {
    __shared__ int l[512];
    const int t = threadIdx.x;
    const int b4 = t * 4;
    int v[4];
    int s = 0;
    #pragma unroll
    for (int j = 0; j < 4; ++j) {
        v[j] = (b4 + j < nb) ? bhist[b4 + j] : 0;
        s += v[j];
    }
    l[t] = s;
    __syncthreads();
    for (int off = 1; off < 512; off <<= 1) {
        int x = (t >= off) ? l[t - off] : 0;
        __syncthreads();
        l[t] += x;
        __syncthreads();
    }
    int run = l[t] - s;   // exclusive prefix
    #pragma unroll
    for (int j = 0; j < 4; ++j) {
        int idx = b4 + j;
        if (idx < nb) { cbase[idx] = run; ccursor[idx] = run; }
        else if (idx == nb) cbase[nb] = run;   // == E
        run += v[j];
    }
}

// multi-split edges into 64-node buckets (contiguous runs per block-tile)
__global__ __launch_bounds__(256) void partition_kernel(const int* __restrict__ dst,
                                                        const int* __restrict__ src,
                                                        const float* __restrict__ vals,
                                                        int* __restrict__ ccursor,
                                                        int2* __restrict__ pay1, int E) {
    __shared__ int hist[NB_MAX];
    __shared__ int base[NB_MAX];
    const int t = threadIdx.x;
    const int ntile = (E + 4095) >> 12;

    for (int tile = blockIdx.x; tile < ntile; tile += gridDim.x) {
        const int e0 = tile << 12;
        #pragma unroll
        for (int j = t; j < NB_MAX; j += 256) hist[j] = 0;
        __syncthreads();

        int bk[16], rk[16];
        #pragma unroll
        for (int j = 0; j < 16; ++j) {
            int e = e0 + j * 256 + t;
            bk[j] = -1;
            if (e < E) {
                bk[j] = dst[e] >> GCB_SHIFT;
                rk[j] = atomicAdd(&hist[bk[j]], 1);
            }
        }
        __syncthreads();

        #pragma unroll
        for (int j = t; j < NB_MAX; j += 256)
            base[j] = hist[j] ? atomicAdd(&ccursor[j], hist[j]) : 0;
        __syncthreads();

        #pragma unroll
        for (int j = 0; j < 16; ++j) {
            int e = e0 + j * 256 + t;
            if (e >= E) continue;
            int d = dst[e];
            int key = ((d & (GCB - 1)) << 17) | src[e];
            pay1[base[bk[j]] + rk[j]] = make_int2(key, __float_as_int(vals[e]));
        }
        __syncthreads();
    }
}

// ---------------- bucket gather: one block per 64-node bucket, LDS fp32 accum ----------------
// accum layout: logical [64][128] stored at row*132 + (c&7)*16 + (c>>3)
// -> a ds_add instruction's 16 lanes (sl=c>>3) hit 16 distinct banks.

#define ACC_ADD(P, M)                                              \
    do {                                                           \
        const float v_ = __int_as_float((P).y);                    \
        float* a_ = &accum[(((unsigned)(P).x) >> 17) * 132 + sl];  \
        atomicAdd(a_ + 0 * 16, v_ * bflo((M).x));                  \
        atomicAdd(a_ + 1 * 16, v_ * bfhi((M).x));                  \
        atomicAdd(a_ + 2 * 16, v_ * bflo((M).y));                  \
        atomicAdd(a_ + 3 * 16, v_ * bfhi((M).y));                  \
        atomicAdd(a_ + 4 * 16, v_ * bflo((M).z));                  \
        atomicAdd(a_ + 5 * 16, v_ * bfhi((M).z));                  \
        atomicAdd(a_ + 6 * 16, v_ * bflo((M).w));                  \
        atomicAdd(a_ + 7 * 16, v_ * bfhi((M).w));                  \
    } while (0)

__global__ __launch_bounds__(256) void bucket_gather(const ushort* __restrict__ support,
                                                     const int* __restrict__ cbase,
                                                     const int2* __restrict__ pay1,
                                                     float* __restrict__ out, int N, int nb) {
    __shared__ float accum[GCB * 132];   // 33 KB
    const int t = threadIdx.x;
    const int g = t >> 4;    // group 0..15, one edge at a time
    const int sl = t & 15;   // owns cols sl*8 .. sl*8+7

    for (int b = blockIdx.x; b < nb; b += gridDim.x) {
        const int beg = cbase[b];
        const int end = cbase[b + 1];
        const int d0 = b << GCB_SHIFT;

        for (int i = t; i < GCB * 132; i += 256) accum[i] = 0.f;
        __syncthreads();

        int i = beg + g;
        for (; i + 16 < end; i += 32) {   // 2 edges per group in flight
            const int2 p0 = pay1[i];
            const int2 p1 = pay1[i + 16];
            const uint4 m0 = *(const uint4*)&support[(size_t)(p0.x & 0x1FFFF) * D + sl * 8];
            const uint4 m1 = *(const uint4*)&support[(size_t)(p1.x & 0x1FFFF) * D + sl * 8];
            ACC_ADD(p0, m0);
            ACC_ADD(p1, m1);
        }
        if (i < end) {
            const int2 p0 = pay1[i];
            const uint4 m0 = *(const uint4*)&support[(size_t)(p0.x & 0x1FFFF) * D + sl * 8];
            ACC_ADD(p0, m0);
        }
        __syncthreads();

        // write out: 512 items, each 16 consecutive cols of one row
        for (int idx = t; idx < GCB * 8; idx += 256) {
            const int row = idx >> 3;
            if (d0 + row < N) {
                const int c0 = (idx & 7) * 16;
                const float* ar = &accum[row * 132];
                float4 o0, o1, o2, o3;
                const int sb = 2 * (idx & 7);   // (c0+k)>>3 = sb + (k>>3)
                o0.x = ar[0 * 16 + sb]; o0.y = ar[1 * 16 + sb];
                o0.z = ar[2 * 16 + sb]; o0.w = ar[3 * 16 + sb];
                o1.x = ar[4 * 16 + sb]; o1.y = ar[5 * 16 + sb];
                o1.z = ar[6 * 16 + sb]; o1.w = ar[7 * 16 + sb];
                o2.x = ar[0 * 16 + sb + 1]; o2.y = ar[1 * 16 + sb + 1];
                o2.z = ar[2 * 16 + sb + 1]; o2.w = ar[3 * 16 + sb + 1];
                o3.x = ar[4 * 16 + sb + 1]; o3.y = ar[5 * 16 + sb + 1];
                o3.z = ar[6 * 16 + sb + 1]; o3.w = ar[7 * 16 + sb + 1];
                float4* op = (float4*)&out[(size_t)(d0 + row) * D + c0];
                op[0] = o0; op[1] = o1; op[2] = o2; op[3] = o3;
            }
        }
        __syncthreads();
    }
}

// ---------------- fallback: atomic scatter (if path constraints unmet) ----------------

__global__ __launch_bounds__(256) void scatter_kernel(const ushort* __restrict__ support,
                                                      const int* __restrict__ dst,
                                                      const int* __restrict__ src,
                                                      const float* __restrict__ vals,
                                                      float* __restrict__ out, int E) {
    const long long tid = (long long)blockIdx.x * blockDim.x + threadIdx.x;
    const int e = (int)(tid >> 6);
    if (e >= E) return;
    const int c = ((int)tid & 63) * 2;

    const int s = src[e];
    const int d = dst[e];
    const float v = vals[e];

    const uint m = *(const uint*)&support[(size_t)s * D + c];
    atomicAdd(&out[(size_t)d * D + c + 0], v * bflo(m));
    atomicAdd(&out[(size_t)d * D + c + 1], v * bfhi(m));
}

// ---------------- launch ----------------

static inline char* align256(char* p) {
    return (char*)(((uintptr_t)p + 255) & ~(uintptr_t)255);
}

extern "C" void kernel_launch(void* const* d_in, const int* in_sizes, int n_in,
                              void* d_out, int out_size, void* d_ws, size_t ws_size,
                              hipStream_t stream) {
    const float* embeds = (const float*)d_in[0];
    const float* W      = (const float*)d_in[1];
    const int*   eidx   = (const int*)d_in[2];
    const float* vals   = (const float*)d_in[3];

    const int N = in_sizes[0] / D;   // 100000
    const int E = in_sizes[3];       // 625000
    const int* dstp = eidx;          // edge_index[0]
    const int* srcp = eidx + E;      // edge_index[1]

    float* out = (float*)d_out;

    // workspace layout (256B-aligned chunks)
    char* p = (char*)d_ws;
    ushort* support = (ushort*)p;  p = align256(p + (size_t)N * D * 2);   // 25.6 MB bf16
    ushort* wT      = (ushort*)p;  p = align256(p + (size_t)D * D * 2);   // 32 KB
    int* bhist      = (int*)p;     p = align256(p + NB_MAX * 4);
    int* cbase      = (int*)p;     p = align256(p + (NB_MAX + 1) * 4);
    int* ccursor    = (int*)p;     p = align256(p + NB_MAX * 4);
    int2* pay1      = (int2*)p;    p = align256(p + (size_t)E * 8);
    const size_t needed = (size_t)(p - (char*)d_ws);

    const int nb = (N + GCB - 1) / GCB;   // 1563 buckets for N=100000
    const bool two_level = (N <= (1 << 17)) && (nb <= NB_MAX - 1) && (ws_size >= needed);

    if (two_level) {
        hipMemsetAsync(bhist, 0, NB_MAX * 4, stream);
        bucket_hist<<<256, 256, 0, stream>>>(dstp, bhist, E, W, wT);
        cscan<<<1, 512, 0, stream>>>(bhist, cbase, ccursor, nb);

        gemm_mfma<<<512, 512, 0, stream>>>(embeds, wT, support, N);

        const int ntile = (E + 4095) / 4096;
        partition_kernel<<<ntile, 256, 0, stream>>>(dstp, srcp, vals, ccursor, pay1, E);
        bucket_gather<<<nb, 256, 0, stream>>>(support, cbase, pay1, out, N, nb);
    } else {
        hipMemsetAsync(bhist, 0, NB_MAX * 4, stream);
        bucket_hist<<<256, 256, 0, stream>>>(dstp, bhist, E, W, wT);  // for wT convert
        gemm_mfma<<<512, 512, 0, stream>>>(embeds, wT, support, N);
        zero_f4_kernel<<<2048, 256, 0, stream>>>((float4*)out, out_size / 4);
        const long long nthreads = (long long)E * 64;
        const int blocks = (int)((nthreads + 255) / 256);
        scatter_kernel<<<blocks, 256, 0, stream>>>(support, dstp, srcp, vals, out, E);
    }
}

// Round 9
// 93.938 us; speedup vs baseline: 5.6194x; 5.6194x over previous
//
#include <hip/hip_runtime.h>

#define D 128       // D_IN == D_OUT == 128
#define CB 256      // nodes per coarse bucket
#define CB_SHIFT 8
#define NB_MAX 512

typedef __attribute__((ext_vector_type(8))) short short8;
typedef __attribute__((ext_vector_type(4))) float f32x4;

__device__ inline ushort f2bf(float f) {   // fp32 -> bf16 RNE
    uint u = __float_as_uint(f);
    uint r = (u + 0x7FFFu + ((u >> 16) & 1u)) >> 16;
    return (ushort)r;
}

// ---------------- utility ----------------

__global__ void zero_f4_kernel(float4* __restrict__ out, int n4) {
    int i = blockIdx.x * blockDim.x + threadIdx.x;
    int stride = gridDim.x * blockDim.x;
    float4 z = make_float4(0.f, 0.f, 0.f, 0.f);
    for (; i < n4; i += stride) out[i] = z;
}

// ---------------- GEMM: 512 thr, 128-row tiles, reg-prefetch pipeline ----------------

__global__ __launch_bounds__(512, 4) void gemm_mfma(const float* __restrict__ embeds,
                                                    const ushort* __restrict__ wT,
                                                    ushort* __restrict__ support, int N) {
    __shared__ ushort aLds[128 * D];   // 32 KB, XOR-swizzled rows
    __shared__ ushort bLds[D * D];     // 32 KB, XOR-swizzled rows (W^T: [n][k])
    const int t = threadIdx.x;         // 0..511
    const int w = t >> 6;              // wave 0..7
    const int l = t & 63;
    const int kgrp = l >> 4;           // 0..3
    const int lan15 = l & 15;

    #pragma unroll
    for (int c = 0; c < 4; ++c) {
        int chunk = c * 512 + t;
        int byteoff = chunk * 16;
        int n = byteoff >> 8;
        int dstoff = byteoff ^ ((n & 7) << 4);
        *(float4*)((char*)bLds + dstoff) = *(const float4*)((const char*)wT + byteoff);
    }

    const int ntiles = (N + 127) >> 7;
    const int prow = t >> 4;           // base row 0..31 (+ j*32)
    const int pcolf = (t & 15) * 8;    // col in floats

    float4 pf[8];
    int tile = blockIdx.x;
    if (tile < ntiles) {
        #pragma unroll
        for (int j = 0; j < 4; ++j) {
            int grow = (tile << 7) + prow + j * 32;
            if (grow < N) {
                const float* s = embeds + (size_t)grow * D + pcolf;
                pf[2 * j] = *(const float4*)s;
                pf[2 * j + 1] = *(const float4*)(s + 4);
            } else {
                pf[2 * j] = make_float4(0.f, 0.f, 0.f, 0.f);
                pf[2 * j + 1] = make_float4(0.f, 0.f, 0.f, 0.f);
            }
        }
    }

    while (tile < ntiles) {
        const int row0 = tile << 7;
        const int next = tile + gridDim.x;

        __syncthreads();
        #pragma unroll
        for (int j = 0; j < 4; ++j) {
            const int rl = prow + j * 32;
            const float4 f0 = pf[2 * j], f1 = pf[2 * j + 1];
            short8 v;
            v[0] = (short)f2bf(f0.x); v[1] = (short)f2bf(f0.y);
            v[2] = (short)f2bf(f0.z); v[3] = (short)f2bf(f0.w);
            v[4] = (short)f2bf(f1.x); v[5] = (short)f2bf(f1.y);
            v[6] = (short)f2bf(f1.z); v[7] = (short)f2bf(f1.w);
            int byteoff = rl * 256 + pcolf * 2;
            *(short8*)((char*)aLds + (byteoff ^ ((rl & 7) << 4))) = v;
        }
        __syncthreads();

        if (next < ntiles) {
            #pragma unroll
            for (int j = 0; j < 4; ++j) {
                int grow = (next << 7) + prow + j * 32;
                if (grow < N) {
                    const float* s = embeds + (size_t)grow * D + pcolf;
                    pf[2 * j] = *(const float4*)s;
                    pf[2 * j + 1] = *(const float4*)(s + 4);
                } else {
                    pf[2 * j] = make_float4(0.f, 0.f, 0.f, 0.f);
                    pf[2 * j + 1] = make_float4(0.f, 0.f, 0.f, 0.f);
                }
            }
        }

        f32x4 acc[8];
        #pragma unroll
        for (int ct = 0; ct < 8; ++ct) acc[ct] = (f32x4)0.0f;

        const int arow = w * 16 + lan15;
        #pragma unroll
        for (int ks = 0; ks < 4; ++ks) {
            const int kbyte = ks * 64 + kgrp * 16;
            const int aoff = (arow * 256 + kbyte) ^ ((arow & 7) << 4);
            short8 af = *(const short8*)((const char*)aLds + aoff);
            #pragma unroll
            for (int ct = 0; ct < 8; ++ct) {
                const int n = ct * 16 + lan15;
                const int boff = (n * 256 + kbyte) ^ ((n & 7) << 4);
                short8 bfr = *(const short8*)((const char*)bLds + boff);
                acc[ct] = __builtin_amdgcn_mfma_f32_16x16x32_bf16(af, bfr, acc[ct], 0, 0, 0);
            }
        }

        #pragma unroll
        for (int r = 0; r < 4; ++r) {
            const int grow = row0 + w * 16 + kgrp * 4 + r;
            if (grow < N) {
                #pragma unroll
                for (int ct = 0; ct < 8; ++ct) {
                    support[(size_t)grow * D + ct * 16 + lan15] = f2bf(acc[ct][r]);
                }
            }
        }
        tile = next;
    }
}

// ---------------- coarse histogram (+ fused W^T convert) ----------------

__global__ __launch_bounds__(256) void bucket_hist(const int* __restrict__ dst,
                                                   int* __restrict__ bhist, int E,
                                                   const float* __restrict__ W,
                                                   ushort* __restrict__ wT) {
    __shared__ int h[NB_MAX];
    const int t = threadIdx.x;
    #pragma unroll
    for (int j = t; j < NB_MAX; j += 256) h[j] = 0;

    // fused: W[128][128] fp32 -> W^T bf16 (first 64 blocks)
    const int gt = blockIdx.x * 256 + t;
    if (gt < D * D) { int r = gt >> 7, c = gt & 127; wT[c * D + r] = f2bf(W[gt]); }
    __syncthreads();

    const int stride = gridDim.x * 256;
    for (int i = gt; i < E; i += stride) atomicAdd(&h[dst[i] >> CB_SHIFT], 1);
    __syncthreads();
    #pragma unroll
    for (int j = t; j < NB_MAX; j += 256)
        if (h[j]) atomicAdd(&bhist[j], h[j]);
}

// exclusive scan of nb (<=512) bucket counts; writes cbase[0..nb], ccursor copy
__global__ __launch_bounds__(512) void cscan(const int* __restrict__ bhist,
                                             int* __restrict__ cbase,
                                             int* __restrict__ ccursor, int nb, int E) {
    __shared__ int l[512];
    const int t = threadIdx.x;
    const int v = (t < nb) ? bhist[t] : 0;
    l[t] = v;
    __syncthreads();
    for (int off = 1; off < 512; off <<= 1) {
        int x = (t >= off) ? l[t - off] : 0;
        __syncthreads();
        l[t] += x;
        __syncthreads();
    }
    const int excl = l[t] - v;
    if (t < nb) { cbase[t] = excl; ccursor[t] = excl; }
    if (t == nb - 1) cbase[nb] = excl + v;   // == E
}

// pass 1: multi-split edges into coarse buckets; 2048-edge tiles -> 306 blocks
__global__ __launch_bounds__(256) void partition_kernel(const int* __restrict__ dst,
                                                        const int* __restrict__ src,
                                                        const float* __restrict__ vals,
                                                        int* __restrict__ ccursor,
                                                        int2* __restrict__ pay1, int E) {
    __shared__ int hist[NB_MAX];
    __shared__ int base[NB_MAX];
    const int t = threadIdx.x;
    const int ntile = (E + 2047) >> 11;

    for (int tile = blockIdx.x; tile < ntile; tile += gridDim.x) {
        const int e0 = tile << 11;
        #pragma unroll
        for (int j = t; j < NB_MAX; j += 256) hist[j] = 0;
        __syncthreads();

        int bk[8], rk[8];
        #pragma unroll
        for (int j = 0; j < 8; ++j) {
            int e = e0 + j * 256 + t;
            bk[j] = -1;
            if (e < E) {
                bk[j] = dst[e] >> CB_SHIFT;
                rk[j] = atomicAdd(&hist[bk[j]], 1);
            }
        }
        __syncthreads();

        #pragma unroll
        for (int j = t; j < NB_MAX; j += 256)
            base[j] = hist[j] ? atomicAdd(&ccursor[j], hist[j]) : 0;
        __syncthreads();

        #pragma unroll
        for (int j = 0; j < 8; ++j) {
            int e = e0 + j * 256 + t;
            if (e >= E) continue;
            int d = dst[e];
            int key = ((d & (CB - 1)) << 17) | src[e];
            pay1[base[bk[j]] + rk[j]] = make_int2(key, __float_as_int(vals[e]));
        }
        __syncthreads();
    }
}

// pass 2: per-bucket LDS hist+scan+place; writes per-node offsets AND final payload
__global__ __launch_bounds__(256) void finefill2(const int2* __restrict__ pay1,
                                                 const int* __restrict__ cbase,
                                                 int* __restrict__ offsets,
                                                 int2* __restrict__ pay,
                                                 int N, int nb, int E) {
    __shared__ int lcnt[CB];   // thread t owns node t of the bucket
    __shared__ int bs[CB];
    __shared__ int lofs[CB];
    const int t = threadIdx.x;

    for (int b = blockIdx.x; b < nb; b += gridDim.x) {
        const int beg = cbase[b];
        const int end = cbase[b + 1];
        const int d0 = b << CB_SHIFT;

        lcnt[t] = 0;
        __syncthreads();
        for (int i = beg + t; i < end; i += 256)
            atomicAdd(&lcnt[((unsigned)pay1[i].x) >> 17], 1);
        __syncthreads();

        const int c = lcnt[t];
        bs[t] = c;
        __syncthreads();
        for (int off = 1; off < 256; off <<= 1) {
            int x = (t >= off) ? bs[t - off] : 0;
            __syncthreads();
            bs[t] += x;
            __syncthreads();
        }
        const int run = bs[t] - c + beg;   // exclusive + bucket base
        if (d0 + t < N) offsets[d0 + t] = run;
        lofs[t] = run;
        __syncthreads();

        for (int i = beg + t; i < end; i += 256) {
            int2 p = pay1[i];
            int dl = ((unsigned)p.x) >> 17;
            int pos = atomicAdd(&lofs[dl], 1);
            pay[pos] = make_int2(p.x & 0x1FFFF, p.y);
        }
        __syncthreads();
    }
    if (blockIdx.x == 0 && t == 0) offsets[N] = E;
}

// ---------------- gather: one 16-lane group per dst node ----------------

#define EDGE_MAC(P, M)                                          \
    do {                                                        \
        const float v_ = __int_as_float((P).y);                 \
        acc[0] += v_ * __uint_as_float(((M).x & 0xFFFFu) << 16);\
        acc[1] += v_ * __uint_as_float((M).x & 0xFFFF0000u);    \
        acc[2] += v_ * __uint_as_float(((M).y & 0xFFFFu) << 16);\
        acc[3] += v_ * __uint_as_float((M).y & 0xFFFF0000u);    \
        acc[4] += v_ * __uint_as_float(((M).z & 0xFFFFu) << 16);\
        acc[5] += v_ * __uint_as_float((M).z & 0xFFFF0000u);    \
        acc[6] += v_ * __uint_as_float(((M).w & 0xFFFFu) << 16);\
        acc[7] += v_ * __uint_as_float((M).w & 0xFFFF0000u);    \
    } while (0)

__global__ __launch_bounds__(256) void gather_kernel(const ushort* __restrict__ support,
                                                     const int* __restrict__ offsets,
                                                     const int2* __restrict__ pay,
                                                     float* __restrict__ out, int N) {
    const int gid = (blockIdx.x * 256 + threadIdx.x) >> 4;   // group id = node id
    const int sl = threadIdx.x & 15;                         // cols sl*8 .. sl*8+7
    if (gid >= N) return;

    const int beg = offsets[gid];
    const int end = offsets[gid + 1];

    float acc[8];
    #pragma unroll
    for (int j = 0; j < 8; ++j) acc[j] = 0.f;

    int i = beg;
    for (; i + 3 < end; i += 4) {   // 4 edges in flight per group
        const int2 p0 = pay[i], p1 = pay[i + 1], p2 = pay[i + 2], p3 = pay[i + 3];
        const uint4 m0 = *(const uint4*)&support[(size_t)p0.x * D + sl * 8];
        const uint4 m1 = *(const uint4*)&support[(size_t)p1.x * D + sl * 8];
        const uint4 m2 = *(const uint4*)&support[(size_t)p2.x * D + sl * 8];
        const uint4 m3 = *(const uint4*)&support[(size_t)p3.x * D + sl * 8];
        EDGE_MAC(p0, m0); EDGE_MAC(p1, m1); EDGE_MAC(p2, m2); EDGE_MAC(p3, m3);
    }
    for (; i + 1 < end; i += 2) {
        const int2 p0 = pay[i], p1 = pay[i + 1];
        const uint4 m0 = *(const uint4*)&support[(size_t)p0.x * D + sl * 8];
        const uint4 m1 = *(const uint4*)&support[(size_t)p1.x * D + sl * 8];
        EDGE_MAC(p0, m0); EDGE_MAC(p1, m1);
    }
    if (i < end) {
        const int2 p0 = pay[i];
        const uint4 m0 = *(const uint4*)&support[(size_t)p0.x * D + sl * 8];
        EDGE_MAC(p0, m0);
    }

    float* o = &out[(size_t)gid * D + sl * 8];
    *(float4*)o       = make_float4(acc[0], acc[1], acc[2], acc[3]);
    *(float4*)(o + 4) = make_float4(acc[4], acc[5], acc[6], acc[7]);
}

// ---------------- fallback: atomic scatter (if path constraints unmet) ----------------

__global__ __launch_bounds__(256) void scatter_kernel(const ushort* __restrict__ support,
                                                      const int* __restrict__ dst,
                                                      const int* __restrict__ src,
                                                      const float* __restrict__ vals,
                                                      float* __restrict__ out, int E) {
    const long long tid = (long long)blockIdx.x * blockDim.x + threadIdx.x;
    const int e = (int)(tid >> 6);
    if (e >= E) return;
    const int c = ((int)tid & 63) * 2;

    const int s = src[e];
    const int d = dst[e];
    const float v = vals[e];

    const uint m = *(const uint*)&support[(size_t)s * D + c];
    const float mx = __uint_as_float((m & 0xFFFFu) << 16);
    const float my = __uint_as_float(m & 0xFFFF0000u);
    atomicAdd(&out[(size_t)d * D + c + 0], v * mx);
    atomicAdd(&out[(size_t)d * D + c + 1], v * my);
}

// ---------------- launch ----------------

static inline char* align256(char* p) {
    return (char*)(((uintptr_t)p + 255) & ~(uintptr_t)255);
}

extern "C" void kernel_launch(void* const* d_in, const int* in_sizes, int n_in,
                              void* d_out, int out_size, void* d_ws, size_t ws_size,
                              hipStream_t stream) {
    const float* embeds = (const float*)d_in[0];
    const float* W      = (const float*)d_in[1];
    const int*   eidx   = (const int*)d_in[2];
    const float* vals   = (const float*)d_in[3];

    const int N = in_sizes[0] / D;   // 100000
    const int E = in_sizes[3];       // 625000
    const int* dstp = eidx;          // edge_index[0]
    const int* srcp = eidx + E;      // edge_index[1]

    float* out = (float*)d_out;

    // workspace layout (256B-aligned chunks)
    char* p = (char*)d_ws;
    ushort* support = (ushort*)p;  p = align256(p + (size_t)N * D * 2);   // 25.6 MB bf16
    ushort* wT      = (ushort*)p;  p = align256(p + (size_t)D * D * 2);   // 32 KB
    int* offsets    = (int*)p;     p = align256(p + (size_t)(N + 1) * 4);
    int* bhist      = (int*)p;     p = align256(p + NB_MAX * 4);
    int* cbase      = (int*)p;     p = align256(p + (NB_MAX + 1) * 4);
    int* ccursor    = (int*)p;     p = align256(p + NB_MAX * 4);
    int2* pay       = (int2*)p;    p = align256(p + (size_t)E * 8);
    int2* pay1      = (int2*)p;    p = align256(p + (size_t)E * 8);
    const size_t needed = (size_t)(p - (char*)d_ws);

    const int nb = (N + CB - 1) / CB;   // 391 coarse buckets
    const bool two_level = (N <= (1 << 17)) && (nb <= NB_MAX) && (ws_size >= needed);

    if (two_level) {
        hipMemsetAsync(bhist, 0, NB_MAX * 4, stream);
        bucket_hist<<<128, 256, 0, stream>>>(dstp, bhist, E, W, wT);
        cscan<<<1, 512, 0, stream>>>(bhist, cbase, ccursor, nb, E);

        gemm_mfma<<<512, 512, 0, stream>>>(embeds, wT, support, N);

        const int ntile = (E + 2047) / 2048;
        partition_kernel<<<ntile, 256, 0, stream>>>(dstp, srcp, vals, ccursor, pay1, E);
        finefill2<<<nb, 256, 0, stream>>>(pay1, cbase, offsets, pay, N, nb, E);
        gather_kernel<<<(N * 16 + 255) / 256, 256, 0, stream>>>(support, offsets, pay, out, N);
    } else {
        hipMemsetAsync(bhist, 0, NB_MAX * 4, stream);
        bucket_hist<<<128, 256, 0, stream>>>(dstp, bhist, E, W, wT);  // for wT convert
        gemm_mfma<<<512, 512, 0, stream>>>(embeds, wT, support, N);
        zero_f4_kernel<<<2048, 256, 0, stream>>>((float4*)out, out_size / 4);
        const long long nthreads = (long long)E * 64;
        const int blocks = (int)((nthreads + 255) / 256);
        scatter_kernel<<<blocks, 256, 0, stream>>>(support, dstp, srcp, vals, out, E);
    }
}